// Round 3
// baseline (12689.300 us; speedup 1.0000x reference)
//
#include <hip/hip_runtime.h>

typedef __bf16 bf16;
typedef __bf16 bf16x4 __attribute__((ext_vector_type(4)));
typedef __bf16 bf16x8 __attribute__((ext_vector_type(8)));
typedef float f32x4 __attribute__((ext_vector_type(4)));
typedef unsigned long long u64;
typedef u64 u64x2 __attribute__((ext_vector_type(2)));
typedef unsigned int u32;

#define T_STEPS 1024
#define BATCH   64
#define DIN     256
#define HID     1024
#define NFB     16            // feature-group blocks (64 features each)
#define SENT    0x7F7F7F7Fu   // two bf16 3.39e38 — unreachable by the RNN

// ---------------------------------------------------------------------------
// Kernel 1: xproj[t][b][h] = sum_d x[b][t][d] * w_ih[h][d]   (bf16 out)
// ---------------------------------------------------------------------------
__global__ __launch_bounds__(256) void xproj_gemm(
    const float* __restrict__ x, const float* __restrict__ w_ih,
    bf16* __restrict__ xproj)
{
    __shared__ bf16 As[128 * 40];
    __shared__ bf16 Bs[128 * 40];
    const int tid = threadIdx.x;
    const int m0 = blockIdx.x * 128;
    const int n0 = blockIdx.y * 128;
    const int w = tid >> 6, lane = tid & 63;
    const int r = lane & 15, q = lane >> 4;

    f32x4 acc[2][8];
    #pragma unroll
    for (int i = 0; i < 2; i++)
        #pragma unroll
        for (int j = 0; j < 8; j++)
            acc[i][j] = (f32x4){0.f, 0.f, 0.f, 0.f};

    for (int kk = 0; kk < 8; kk++) {
        const int k0 = kk * 32;
        __syncthreads();
        #pragma unroll
        for (int j = 0; j < 4; j++) {
            int u = tid + j * 256;
            int row = u >> 3, c4 = u & 7;
            float4 fa = *(const float4*)&x[(size_t)(m0 + row) * DIN + k0 + c4 * 4];
            bf16x4 va = { (bf16)fa.x, (bf16)fa.y, (bf16)fa.z, (bf16)fa.w };
            *(bf16x4*)&As[row * 40 + c4 * 4] = va;
            float4 fb = *(const float4*)&w_ih[(size_t)(n0 + row) * DIN + k0 + c4 * 4];
            bf16x4 vb = { (bf16)fb.x, (bf16)fb.y, (bf16)fb.z, (bf16)fb.w };
            *(bf16x4*)&Bs[row * 40 + c4 * 4] = vb;
        }
        __syncthreads();
        bf16x8 a0 = *(const bf16x8*)&As[(w * 32 + r) * 40 + q * 8];
        bf16x8 a1 = *(const bf16x8*)&As[(w * 32 + 16 + r) * 40 + q * 8];
        #pragma unroll
        for (int nt = 0; nt < 8; nt++) {
            bf16x8 bb = *(const bf16x8*)&Bs[(nt * 16 + r) * 40 + q * 8];
            acc[0][nt] = __builtin_amdgcn_mfma_f32_16x16x32_bf16(a0, bb, acc[0][nt], 0, 0, 0);
            acc[1][nt] = __builtin_amdgcn_mfma_f32_16x16x32_bf16(a1, bb, acc[1][nt], 0, 0, 0);
        }
    }

    #pragma unroll
    for (int mi = 0; mi < 2; mi++)
        #pragma unroll
        for (int nt = 0; nt < 8; nt++)
            #pragma unroll
            for (int reg = 0; reg < 4; reg++) {
                int gm = m0 + w * 32 + mi * 16 + q * 4 + reg;   // x row = b*T + t
                int n  = n0 + nt * 16 + r;
                int b  = gm >> 10, t = gm & 1023;
                xproj[(((t << 6) + b) << 10) + n] = (bf16)acc[mi][nt][reg];
            }
}

// ---------------------------------------------------------------------------
// Kernel 2: persistent recurrence, 4-stream latency-hiding version.
//
// B=64 splits into 4 independent 16-batch streams (recurrence couples only
// along features). 16 blocks x 256 thr (4 waves = 4 K-quarters), one block
// per 64-feature group; each block processes streams 0..3 round-robin per
// timestep. The agent-scope store->L3->poll-load round trip for stream s is
// hidden under the other streams' compute: poll loads for qstep u are issued
// speculatively at qstep u-2, targeting data stored at u-4.
//
// ROUND-3 FIX: the in-loop __syncthreads() was draining vmcnt(0) each qstep
// (hipcc emits a full s_waitcnt before s_barrier), synchronously completing
// the just-issued speculative polls + store acks -> 4 RTTs per timestep.
// Replaced with raw s_barrier + lgkmcnt(0)-only wait (8-phase-template
// pattern): poll loads now stay in flight across barriers. Protocol safety:
// each qstep's stage-1 counted vmcnt wait (FIFO counting) forces completion
// of all VMEM older than 2 qsteps, so sentinel-store -> data-store ordering
// to the same address (12 qsteps apart) still holds; Red parity WAR is still
// barrier-ordered (reads of parity p precede that wave's next barrier
// arrival; the conflicting write follows passage of that same barrier).
//
// hbuf layout: [slot 8][global batch 64][feat 1024] bf16 (stream-major
// batches: stream s owns global batches s*16..s*16+15). A u32 word is either
// SENT (unwritten this generation) or final data (u32 stores are atomic).
// Ring of 8 slots; producer re-sentinels its region of slot (t+4)&7 during
// step t. Skew between blocks within a stream is <=1 step by the dependency
// chain.
// ---------------------------------------------------------------------------
__device__ __forceinline__ void poll_issue(u64* dst, const u64* src)
{
    #pragma unroll
    for (int j = 0; j < 8; j++) {
        dst[2 * j]     = __hip_atomic_load(src + (size_t)j * 8,
                                           __ATOMIC_RELAXED, __HIP_MEMORY_SCOPE_AGENT);
        dst[2 * j + 1] = __hip_atomic_load(src + (size_t)j * 8 + 1,
                                           __ATOMIC_RELAXED, __HIP_MEMORY_SCOPE_AGENT);
    }
    // pin the issue point: loads may not sink below, later code may not hoist above
    __builtin_amdgcn_sched_barrier(0);
}

__device__ __forceinline__ int poll_clean(const u64* b)
{
    int ok = 1;
    #pragma unroll
    for (int j = 0; j < 16; j++) {
        u64 v = b[j];
        ok &= ((u32)v != SENT);
        ok &= ((u32)(v >> 32) != SENT);
    }
    return __all(ok);
}

// raw workgroup barrier that does NOT drain vmcnt: orders only LDS ops
__device__ __forceinline__ void lds_barrier()
{
    __builtin_amdgcn_sched_barrier(0);
    asm volatile("s_waitcnt lgkmcnt(0)" ::: "memory");
    __builtin_amdgcn_s_barrier();
    __builtin_amdgcn_sched_barrier(0);
}

__global__ __launch_bounds__(256, 1) void rnn_rec(
    const float* __restrict__ w_hh, const float* __restrict__ b_mod,
    const bf16* __restrict__ xproj, u64* __restrict__ hbuf,
    float* __restrict__ hT)
{
    __shared__ bf16 Wl[64 * 1032];        // 132 KB, +8 bf16 row pad
    __shared__ f32x4 Red[2][12][64];      // 24.5 KB: [qstep parity][nt*3+s][lane]

    const int tid  = threadIdx.x;
    const int f0   = (int)blockIdx.x * 64;
    const int kq   = tid >> 6;            // wave = K quarter (0..3)
    const int lane = tid & 63;
    const int r = lane & 15, q = lane >> 4;

    // Stage W rows f0..f0+63 (fp32 -> bf16) into LDS, once.
    for (int j = 0; j < 64; j++) {
        int u = tid + j * 256;            // float4 units, 0..16383
        int row = u >> 8, c4 = u & 255;
        float4 f = *(const float4*)&w_hh[(size_t)(f0 + row) * HID + c4 * 4];
        bf16x4 v = { (bf16)f.x, (bf16)f.y, (bf16)f.z, (bf16)f.w };
        *(bf16x4*)&Wl[row * 1032 + c4 * 4] = v;
    }
    const int myF = f0 + kq * 16 + r;     // feature this lane finalizes
    const float bc = b_mod[myF];
    __syncthreads();

    // Hoist B fragments: 4 n-tiles x 8 k-steps (loop-invariant, 128 VGPRs;
    // 1 block/CU (LDS-bound) -> 1 wave/SIMD -> up to 512 VGPRs available).
    bf16x8 Bf[4][8];
    #pragma unroll
    for (int nt = 0; nt < 4; nt++)
        #pragma unroll
        for (int ks = 0; ks < 8; ks++)
            Bf[nt][ks] = *(const bf16x8*)&Wl[(nt * 16 + r) * 1032 + kq * 256 + ks * 32 + q * 8];

    u32* hbuf32 = (u32*)hbuf;
    // per-lane A-fragment offset inside a slot, in u64 units:
    // bytes = (global batch row r of my stream)*2048 + kq*512 + q*16
    // (stream base s*16*2048 B = s*4096 u64 is added at poll time)
    const int fragU = r * 256 + kq * 64 + q * 2;

    // xproj prefetch for t=0, all 4 streams
    float xpv[4][4];
    #pragma unroll
    for (int s = 0; s < 4; s++)
        #pragma unroll
        for (int reg = 0; reg < 4; reg++)
            xpv[s][reg] = (float)xproj[((s * 16 + q * 4 + reg) << 10) + myF];

    // two poll buffers (qstep parity); prologue: issue for (t=0,s=0),(t=0,s=1)
    // slot 0 is h0 = 0 -> passes instantly.
    u64 pb[2][16];
    poll_issue(pb[0], hbuf + 0 * 4096 + fragU);
    poll_issue(pb[1], hbuf + 1 * 4096 + fragU);

    for (int t = 0; t < T_STEPS; t++) {
        const int rp = t & 7, wp = (t + 1) & 7, sp = (t + 4) & 7;
        #pragma unroll
        for (int s = 0; s < 4; s++) {
            const int par = s & 1;

            // ---- 1. check (speculative loads from qstep u-2); retry if dirty ----
            if (!poll_clean(pb[par])) {
                const u64* src = hbuf + (size_t)rp * 16384 + s * 4096 + fragU;
                do { poll_issue(pb[par], src); } while (!poll_clean(pb[par]));
            }

            // ---- 2. MFMA: z partials for my K-quarter, 4 n-tiles ----
            f32x4 acc[4];
            #pragma unroll
            for (int nt = 0; nt < 4; nt++) acc[nt] = (f32x4){0.f, 0.f, 0.f, 0.f};
            #pragma unroll
            for (int ks = 0; ks < 8; ks++) {
                u64x2 w2 = { pb[par][2 * ks], pb[par][2 * ks + 1] };
                bf16x8 af = __builtin_bit_cast(bf16x8, w2);
                #pragma unroll
                for (int nt = 0; nt < 4; nt++)
                    acc[nt] = __builtin_amdgcn_mfma_f32_16x16x32_bf16(af, Bf[nt][ks], acc[nt], 0, 0, 0);
            }

            // ---- 3. speculative poll issue for qstep u+2 (stream s+2) ----
            {
                const int s2 = (s + 2) & 3;
                const int t2 = t + (s >> 1);          // s=2,3 -> next timestep
                if (t2 < T_STEPS) {
                    const int rp2 = t2 & 7;
                    poll_issue(pb[par], hbuf + (size_t)rp2 * 16384 + s2 * 4096 + fragU);
                }
            }

            // ---- 4. K-partials for the n-tiles I don't finalize -> LDS ----
            #pragma unroll
            for (int nt = 0; nt < 4; nt++) {
                if (nt == kq) continue;
                const int sidx = (kq - nt - 1) & 3;   // 0..2
                Red[par][nt * 3 + sidx][lane] = acc[nt];
            }
            lds_barrier();   // LDS-only barrier: poll loads stay in flight
            // (single barrier per qstep: parity double-buffer; this parity's
            //  reads finish before the next same-parity write, which sits
            //  behind the *next* qstep's barrier in every wave's program order)

            // ---- 5. finalize my n-tile (nt == kq): 16 feat x 16 batch ----
            f32x4 z4 = acc[kq];
            #pragma unroll
            for (int si = 0; si < 3; si++) z4 += Red[par][kq * 3 + si][lane];
            float hv4[4];
            #pragma unroll
            for (int reg = 0; reg < 4; reg++) {
                float z = z4[reg] + xpv[s][reg];
                hv4[reg] = copysignf(fmaxf(fabsf(z) + bc, 0.0f), z);
            }

            // ---- 6. stores ----
            if (t == T_STEPS - 1) {
                float4 o; o.x = hv4[0]; o.y = hv4[1]; o.z = hv4[2]; o.w = hv4[3];
                *(float4*)&hT[myF * 64 + s * 16 + q * 4] = o;   // fp32 [H][B]
            } else {
                #pragma unroll
                for (int reg = 0; reg < 4; reg++) {
                    const int b = s * 16 + q * 4 + reg;         // GLOBAL batch (stream-major)
                    float other = __shfl_xor(hv4[reg], 1);
                    if ((r & 1) == 0) {
                        u32 lo = (u32)__builtin_bit_cast(unsigned short, (bf16)hv4[reg]);
                        u32 hi = (u32)__builtin_bit_cast(unsigned short, (bf16)other);
                        // h_{t+1} data into slot wp  ([slot][global batch][feat])
                        __hip_atomic_store(&hbuf32[(size_t)wp * 32768 + b * 512 + (myF >> 1)],
                                           lo | (hi << 16), __ATOMIC_RELAXED, __HIP_MEMORY_SCOPE_AGENT);
                        // re-sentinel my region of slot (t+4)&7
                        __hip_atomic_store(&hbuf32[(size_t)sp * 32768 + b * 512 + (myF >> 1)],
                                           SENT, __ATOMIC_RELAXED, __HIP_MEMORY_SCOPE_AGENT);
                    }
                }
                // prefetch next step's xproj for this stream (consumed 4 qsteps later)
                #pragma unroll
                for (int reg = 0; reg < 4; reg++) {
                    const int b = s * 16 + q * 4 + reg;
                    xpv[s][reg] = (float)xproj[((size_t)(t + 1) << 16) + (b << 10) + myF];
                }
            }
        }
    }
}

// ---------------------------------------------------------------------------
// Kernel 3: out[b][c] = hT[:,b] . w_fc[c,:] + b_fc[c]   (fp32)
// ---------------------------------------------------------------------------
__global__ __launch_bounds__(256) void fc_head(
    const float* __restrict__ hT, const float* __restrict__ w_fc,
    const float* __restrict__ b_fc, float* __restrict__ out)
{
    const int tid = threadIdx.x;
    const int b = tid & 63;
    const int c = blockIdx.x * 4 + (tid >> 6);
    float acc = b_fc[c];
    #pragma unroll 8
    for (int k = 0; k < HID; k++)
        acc = fmaf(hT[k * 64 + b], w_fc[(size_t)c * HID + k], acc);
    out[b * 1000 + c] = acc;
}

// ---------------------------------------------------------------------------
extern "C" void kernel_launch(void* const* d_in, const int* in_sizes, int n_in,
                              void* d_out, int out_size, void* d_ws, size_t ws_size,
                              hipStream_t stream)
{
    const float* x     = (const float*)d_in[0];
    const float* w_ih  = (const float*)d_in[1];
    const float* w_hh  = (const float*)d_in[2];
    const float* b_mod = (const float*)d_in[3];
    const float* w_fc  = (const float*)d_in[4];
    const float* b_fc  = (const float*)d_in[5];
    float* out = (float*)d_out;

    char* ws = (char*)d_ws;
    // ws layout:
    //   [0, 128 MiB)              xproj bf16  [T][B][H]
    //   [+0, +1 MiB)              hbuf bf16   ring[8][B][H]
    //   [+1 MiB, +1.25 MiB)       hT fp32     [H][B]
    bf16*  xproj = (bf16*)ws;
    u64*   hbuf  = (u64*)(ws + 134217728);
    float* hT    = (float*)(ws + 134217728 + 1048576);

    // ring init: slot 0 = h0 = 0 (valid data), slots 1..7 = sentinel bytes
    hipMemsetAsync(hbuf, 0, 131072, stream);
    hipMemsetAsync((char*)hbuf + 131072, 0x7F, 7 * 131072, stream);

    dim3 g1(512, 8);
    xproj_gemm<<<g1, 256, 0, stream>>>(x, w_ih, xproj);
    rnn_rec<<<NFB, 256, 0, stream>>>(w_hh, b_mod, xproj, hbuf, hT);
    fc_head<<<250, 256, 0, stream>>>(hT, w_fc, b_fc, out);
}

// Round 7
// 12424.440 us; speedup vs baseline: 1.0213x; 1.0213x over previous
//
#include <hip/hip_runtime.h>

typedef __bf16 bf16;
typedef __bf16 bf16x4 __attribute__((ext_vector_type(4)));
typedef __bf16 bf16x8 __attribute__((ext_vector_type(8)));
typedef float f32x4 __attribute__((ext_vector_type(4)));
typedef int   i32x4 __attribute__((ext_vector_type(4)));
typedef unsigned long long u64;
typedef unsigned int u32;

#define T_STEPS 1024
#define BATCH   64
#define DIN     256
#define HID     1024
#define NFB     16            // feature-group blocks (64 features each)
#define SENT    0x7F7F7F7Fu   // two bf16 3.39e38 — unreachable by the RNN

// ---------------------------------------------------------------------------
// Kernel 1: xproj[t][b][h] = sum_d x[b][t][d] * w_ih[h][d]   (bf16 out)
// ---------------------------------------------------------------------------
__global__ __launch_bounds__(256) void xproj_gemm(
    const float* __restrict__ x, const float* __restrict__ w_ih,
    bf16* __restrict__ xproj)
{
    __shared__ bf16 As[128 * 40];
    __shared__ bf16 Bs[128 * 40];
    const int tid = threadIdx.x;
    const int m0 = blockIdx.x * 128;
    const int n0 = blockIdx.y * 128;
    const int w = tid >> 6, lane = tid & 63;
    const int r = lane & 15, q = lane >> 4;

    f32x4 acc[2][8];
    #pragma unroll
    for (int i = 0; i < 2; i++)
        #pragma unroll
        for (int j = 0; j < 8; j++)
            acc[i][j] = (f32x4){0.f, 0.f, 0.f, 0.f};

    for (int kk = 0; kk < 8; kk++) {
        const int k0 = kk * 32;
        __syncthreads();
        #pragma unroll
        for (int j = 0; j < 4; j++) {
            int u = tid + j * 256;
            int row = u >> 3, c4 = u & 7;
            float4 fa = *(const float4*)&x[(size_t)(m0 + row) * DIN + k0 + c4 * 4];
            bf16x4 va = { (bf16)fa.x, (bf16)fa.y, (bf16)fa.z, (bf16)fa.w };
            *(bf16x4*)&As[row * 40 + c4 * 4] = va;
            float4 fb = *(const float4*)&w_ih[(size_t)(n0 + row) * DIN + k0 + c4 * 4];
            bf16x4 vb = { (bf16)fb.x, (bf16)fb.y, (bf16)fb.z, (bf16)fb.w };
            *(bf16x4*)&Bs[row * 40 + c4 * 4] = vb;
        }
        __syncthreads();
        bf16x8 a0 = *(const bf16x8*)&As[(w * 32 + r) * 40 + q * 8];
        bf16x8 a1 = *(const bf16x8*)&As[(w * 32 + 16 + r) * 40 + q * 8];
        #pragma unroll
        for (int nt = 0; nt < 8; nt++) {
            bf16x8 bb = *(const bf16x8*)&Bs[(nt * 16 + r) * 40 + q * 8];
            acc[0][nt] = __builtin_amdgcn_mfma_f32_16x16x32_bf16(a0, bb, acc[0][nt], 0, 0, 0);
            acc[1][nt] = __builtin_amdgcn_mfma_f32_16x16x32_bf16(a1, bb, acc[1][nt], 0, 0, 0);
        }
    }

    #pragma unroll
    for (int mi = 0; mi < 2; mi++)
        #pragma unroll
        for (int nt = 0; nt < 8; nt++)
            #pragma unroll
            for (int reg = 0; reg < 4; reg++) {
                int gm = m0 + w * 32 + mi * 16 + q * 4 + reg;   // x row = b*T + t
                int n  = n0 + nt * 16 + r;
                int b  = gm >> 10, t = gm & 1023;
                xproj[(((t << 6) + b) << 10) + n] = (bf16)acc[mi][nt][reg];
            }
}

// ---------------------------------------------------------------------------
// Kernel 2: persistent recurrence, 4-stream, CONSUME-TIME POLL ONLY.
//
// Round-7 design decision: every "speculative register poll" variant
// (r4-r6) aborts — an asm global_load whose vmcnt wait lives in a LATER
// block has a delayed-writeback hazard: hardware writes the output VGPRs
// after the asm block "completes", and any allocator spill/copy/reuse in
// that window gets clobbered (wild addresses -> memory fault). The ONLY
// proven-safe asm shape is issue + s_waitcnt vmcnt(0) + check in ONE block
// (round 0). So: keep the 4-stream structure, but poll synchronously at
// consume time. The win vs the 5.0 ms baseline comes from slack, not
// overlap: stream s's h was stored 4 qsteps (~3000+ cy) before its
// consume-poll, so store-visibility is long done, retries ~never happen,
// and the poll costs one clean L3 read RTT instead of baseline's
// visibility-wait + retry-quantized ~11,300 cy/step.
//
// All other VMEM is compiler-tracked (proven r2/r3): relaxed-agent atomic
// stores for h data + sentinels, plain ushort loads for xproj (raw bits
// consumed NEXT qstep, converted at use, so the compiler's counted wait
// lands after that qstep's poll drain -> free).
//
// hbuf layout: [slot 8][global batch 64][feat 1024] bf16, stream s owns
// batches s*16..s*16+15. A u32 word is either SENT or final data (u32
// stores atomic). Ring of 8 slots; producer re-sentinels its region of
// slot (t+4)&7 during step t; its own step-t+1 poll's vmcnt(0) drains the
// sentinel store before the matching data store (step t+3) can issue, and
// skew <=1 step means readers of that slot's old generation are >=3 steps
// done. Stale-data race excluded: a consumer at step t sees the producer's
// step-(t-4) re-sentinel (drained by producer's step-(t-3) poll, and
// consumer lags producer by <=1 step).
// ---------------------------------------------------------------------------

// issue 8 dwordx4 + vmcnt(0) + registers final at block exit (r0-proven)
#define POLL_FORCE(BUF, srcp)                                          \
  asm volatile(                                                        \
    "global_load_dwordx4 %0, %8, off sc0 sc1\n\t"                      \
    "global_load_dwordx4 %1, %8, off offset:64 sc0 sc1\n\t"            \
    "global_load_dwordx4 %2, %8, off offset:128 sc0 sc1\n\t"           \
    "global_load_dwordx4 %3, %8, off offset:192 sc0 sc1\n\t"           \
    "global_load_dwordx4 %4, %8, off offset:256 sc0 sc1\n\t"           \
    "global_load_dwordx4 %5, %8, off offset:320 sc0 sc1\n\t"           \
    "global_load_dwordx4 %6, %8, off offset:384 sc0 sc1\n\t"           \
    "global_load_dwordx4 %7, %8, off offset:448 sc0 sc1\n\t"           \
    "s_waitcnt vmcnt(0)"                                               \
    : "=&v"(BUF[0]), "=&v"(BUF[1]), "=&v"(BUF[2]), "=&v"(BUF[3]),      \
      "=&v"(BUF[4]), "=&v"(BUF[5]), "=&v"(BUF[6]), "=&v"(BUF[7])       \
    : "v"(srcp) : "memory")

__device__ __forceinline__ int poll_clean4(const i32x4* b)
{
    int ok = 1;
    #pragma unroll
    for (int j = 0; j < 8; j++)
        #pragma unroll
        for (int k2 = 0; k2 < 4; k2++)
            ok &= (b[j][k2] != (int)SENT);
    return __all(ok);
}

// raw workgroup barrier that does NOT drain vmcnt: orders only LDS ops
__device__ __forceinline__ void lds_barrier()
{
    __builtin_amdgcn_sched_barrier(0);
    asm volatile("s_waitcnt lgkmcnt(0)" ::: "memory");
    __builtin_amdgcn_s_barrier();
    __builtin_amdgcn_sched_barrier(0);
}

__global__ __launch_bounds__(256, 1) void rnn_rec(
    const float* __restrict__ w_hh, const float* __restrict__ b_mod,
    const bf16* __restrict__ xproj, u64* __restrict__ hbuf,
    float* __restrict__ hT)
{
    __shared__ bf16 Wl[64 * 1032];        // 132 KB, +8 bf16 row pad
    __shared__ f32x4 Red[2][12][64];      // 24.5 KB: [qstep parity][nt*3+s][lane]

    const int tid  = threadIdx.x;
    const int f0   = (int)blockIdx.x * 64;
    const int kq   = tid >> 6;            // wave = K quarter (0..3)
    const int lane = tid & 63;
    const int r = lane & 15, q = lane >> 4;

    // Stage W rows f0..f0+63 (fp32 -> bf16) into LDS, once.
    for (int j = 0; j < 64; j++) {
        int u = tid + j * 256;            // float4 units, 0..16383
        int row = u >> 8, c4 = u & 255;
        float4 f = *(const float4*)&w_hh[(size_t)(f0 + row) * HID + c4 * 4];
        bf16x4 v = { (bf16)f.x, (bf16)f.y, (bf16)f.z, (bf16)f.w };
        *(bf16x4*)&Wl[row * 1032 + c4 * 4] = v;
    }
    const int myF = f0 + kq * 16 + r;     // feature this lane finalizes
    const float bc = b_mod[myF];
    __syncthreads();

    // Hoist B fragments: 4 n-tiles x 8 k-steps (loop-invariant, 128 VGPRs;
    // 1 block/CU (LDS-bound) -> up to 512 VGPRs/wave available).
    bf16x8 Bf[4][8];
    #pragma unroll
    for (int nt = 0; nt < 4; nt++)
        #pragma unroll
        for (int ks = 0; ks < 8; ks++)
            Bf[nt][ks] = *(const bf16x8*)&Wl[(nt * 16 + r) * 1032 + kq * 256 + ks * 32 + q * 8];

    u32* hbuf32 = (u32*)hbuf;
    // per-lane A-fragment byte offset inside a (slot,stream) region
    const int fragB = r * 2048 + kq * 512 + q * 16;

    // xproj raw-bit prefetch regs: XR[s][reg] holds x for the CURRENT t of
    // stream s (loaded one qstep in advance, converted only at use).
    u32 XR[4][4];
    #pragma unroll
    for (int s = 0; s < 4; s++) {
        const unsigned short* xb =
            (const unsigned short*)xproj + (((s * 16 + q * 4) << 10) + myF);
        XR[s][0] = xb[0]; XR[s][1] = xb[1024];
        XR[s][2] = xb[2048]; XR[s][3] = xb[3072];
    }

    for (int t = 0; t < T_STEPS; t++) {
        const int rp = t & 7, wp = (t + 1) & 7, sp = (t + 4) & 7;
        #pragma unroll
        for (int s = 0; s < 4; s++) {
            // ---- 1. consume-time poll (single proven asm block; data is
            //         4 qsteps old -> first try clean, cost = 1 load RTT) ----
            const char* rsrc = (const char*)hbuf
                + (size_t)rp * 131072 + s * 32768 + fragB;
            i32x4 A[8];
            int tries = 0;
            do { POLL_FORCE(A, rsrc); }
            while (!poll_clean4(A) && ++tries < (1 << 16));

            // ---- 1b. xproj raw loads for (t+1, s): issued here, counted
            //          wait lands after next qstep's poll drain -> free ----
            u32 xn0 = 0, xn1 = 0, xn2 = 0, xn3 = 0;
            if (t + 1 < T_STEPS) {
                const unsigned short* xb = (const unsigned short*)xproj
                    + (((size_t)(t + 1) << 16) + ((s * 16 + q * 4) << 10) + myF);
                xn0 = xb[0]; xn1 = xb[1024]; xn2 = xb[2048]; xn3 = xb[3072];
            }

            // ---- 2. MFMA: z partials for my K-quarter, 4 n-tiles ----
            f32x4 acc[4];
            acc[0] = acc[1] = acc[2] = acc[3] = (f32x4){0.f, 0.f, 0.f, 0.f};
            #pragma unroll
            for (int ks = 0; ks < 8; ks++) {
                bf16x8 af = __builtin_bit_cast(bf16x8, A[ks]);
                #pragma unroll
                for (int nt = 0; nt < 4; nt++)
                    acc[nt] = __builtin_amdgcn_mfma_f32_16x16x32_bf16(
                                  af, Bf[nt][ks], acc[nt], 0, 0, 0);
            }

            // ---- 3. K-partials for the n-tiles I don't finalize -> LDS ----
            #pragma unroll
            for (int nt = 0; nt < 4; nt++) {
                if (nt == kq) continue;
                const int sidx = (kq - nt - 1) & 3;   // 0..2
                Red[s & 1][nt * 3 + sidx][lane] = acc[nt];
            }
            lds_barrier();   // lgkm-only: stores/xproj loads stay in flight
            // (parity double-buffer: this parity's reads finish before the
            //  next same-parity write, which sits behind the next qstep's
            //  barrier in every wave's program order)

            // ---- 4. finalize my n-tile (nt == kq): 16 feat x 16 batch ----
            f32x4 z4 = acc[kq];
            #pragma unroll
            for (int si = 0; si < 3; si++)
                z4 += Red[s & 1][kq * 3 + si][lane];
            float hv4[4];
            #pragma unroll
            for (int reg = 0; reg < 4; reg++) {
                float xf = __builtin_bit_cast(float, XR[s][reg] << 16);
                float z = z4[reg] + xf;
                hv4[reg] = copysignf(fmaxf(fabsf(z) + bc, 0.0f), z);
            }

            // ---- 5. output ----
            if (t == T_STEPS - 1) {
                float4 o; o.x = hv4[0]; o.y = hv4[1]; o.z = hv4[2]; o.w = hv4[3];
                *(float4*)&hT[myF * 64 + s * 16 + q * 4] = o;   // fp32 [H][B]
            } else {
                #pragma unroll
                for (int reg = 0; reg < 4; reg++) {
                    const int b = s * 16 + q * 4 + reg;   // GLOBAL batch
                    float other = __shfl_xor(hv4[reg], 1);
                    if ((r & 1) == 0) {
                        u32 lo = (u32)__builtin_bit_cast(unsigned short, (bf16)hv4[reg]);
                        u32 hi = (u32)__builtin_bit_cast(unsigned short, (bf16)other);
                        // h_{t+1} data into slot wp
                        __hip_atomic_store(&hbuf32[(size_t)wp * 32768 + b * 512 + (myF >> 1)],
                                           lo | (hi << 16), __ATOMIC_RELAXED, __HIP_MEMORY_SCOPE_AGENT);
                        // re-sentinel my region of slot (t+4)&7
                        __hip_atomic_store(&hbuf32[(size_t)sp * 32768 + b * 512 + (myF >> 1)],
                                           SENT, __ATOMIC_RELAXED, __HIP_MEMORY_SCOPE_AGENT);
                    }
                }
            }

            // ---- 6. roll xproj regs for next t of this stream ----
            XR[s][0] = xn0; XR[s][1] = xn1; XR[s][2] = xn2; XR[s][3] = xn3;
        }
    }
}

// ---------------------------------------------------------------------------
// Kernel 3: out[b][c] = hT[:,b] . w_fc[c,:] + b_fc[c]   (fp32)
// ---------------------------------------------------------------------------
__global__ __launch_bounds__(256) void fc_head(
    const float* __restrict__ hT, const float* __restrict__ w_fc,
    const float* __restrict__ b_fc, float* __restrict__ out)
{
    const int tid = threadIdx.x;
    const int b = tid & 63;
    const int c = blockIdx.x * 4 + (tid >> 6);
    float acc = b_fc[c];
    #pragma unroll 8
    for (int k = 0; k < HID; k++)
        acc = fmaf(hT[k * 64 + b], w_fc[(size_t)c * HID + k], acc);
    out[b * 1000 + c] = acc;
}

// ---------------------------------------------------------------------------
extern "C" void kernel_launch(void* const* d_in, const int* in_sizes, int n_in,
                              void* d_out, int out_size, void* d_ws, size_t ws_size,
                              hipStream_t stream)
{
    const float* x     = (const float*)d_in[0];
    const float* w_ih  = (const float*)d_in[1];
    const float* w_hh  = (const float*)d_in[2];
    const float* b_mod = (const float*)d_in[3];
    const float* w_fc  = (const float*)d_in[4];
    const float* b_fc  = (const float*)d_in[5];
    float* out = (float*)d_out;

    char* ws = (char*)d_ws;
    // ws layout:
    //   [0, 128 MiB)              xproj bf16  [T][B][H]
    //   [+0, +1 MiB)              hbuf bf16   ring[8][B][H]
    //   [+1 MiB, +1.25 MiB)       hT fp32     [H][B]
    bf16*  xproj = (bf16*)ws;
    u64*   hbuf  = (u64*)(ws + 134217728);
    float* hT    = (float*)(ws + 134217728 + 1048576);

    // ring init: slot 0 = h0 = 0 (valid data), slots 1..7 = sentinel bytes
    hipMemsetAsync(hbuf, 0, 131072, stream);
    hipMemsetAsync((char*)hbuf + 131072, 0x7F, 7 * 131072, stream);

    dim3 g1(512, 8);
    xproj_gemm<<<g1, 256, 0, stream>>>(x, w_ih, xproj);
    rnn_rec<<<NFB, 256, 0, stream>>>(w_hh, b_mod, xproj, hbuf, hT);
    fc_head<<<250, 256, 0, stream>>>(hT, w_fc, b_fc, out);
}